// Round 1
// baseline (280.921 us; speedup 1.0000x reference)
//
#include <hip/hip_runtime.h>
#include <hip/hip_bf16.h>

#define D_DIM 128
#define TILE 128
#define LDS_K (D_DIM + 8)   // +8 bf16 = +16B pad -> 4-bank row rotation, 2-way conflicts (free)

typedef __attribute__((ext_vector_type(8))) short short8;   // 8 bf16 in 4 VGPRs (MFMA A/B frag)
typedef __attribute__((ext_vector_type(4))) float floatx4;  // MFMA C/D frag

// ---------------------------------------------------------------------------
// prep: round fp32 rows to bf16 (stored to ws) and compute row sum-of-squares
// of the ROUNDED values (so d2 = ||a_hat - b_hat||^2 >= 0 exactly).
// 64 lanes per row, 2 elements per lane; 4 rows per 256-thread block.
// ---------------------------------------------------------------------------
__global__ void prep_kernel(const float* __restrict__ za, const float* __restrict__ zb,
                            __hip_bfloat16* __restrict__ abf, __hip_bfloat16* __restrict__ bbf,
                            float* __restrict__ a2, float* __restrict__ b2, int N) {
    int r = blockIdx.x * 4 + (threadIdx.x >> 6);
    int lane = threadIdx.x & 63;
    const float* src; __hip_bfloat16* dst; float* nrm; int row;
    if (r < N) { src = za; dst = abf; nrm = a2; row = r; }
    else       { src = zb; dst = bbf; nrm = b2; row = r - N; }
    const float2 v = ((const float2*)(src + (size_t)row * D_DIM))[lane];
    __hip_bfloat16 h0 = __float2bfloat16(v.x);
    __hip_bfloat16 h1 = __float2bfloat16(v.y);
    float f0 = __bfloat162float(h0), f1 = __bfloat162float(h1);
    float ss = f0 * f0 + f1 * f1;
    ushort2 st;
    st.x = *(const unsigned short*)&h0;
    st.y = *(const unsigned short*)&h1;
    ((ushort2*)(dst + (size_t)row * D_DIM))[lane] = st;
    #pragma unroll
    for (int off = 32; off; off >>= 1) ss += __shfl_down(ss, off, 64);
    if (lane == 0) nrm[row] = ss;
}

// ---------------------------------------------------------------------------
// dist: 128x128 output tile per block, 4 waves in 2x2, each wave a 64x64
// subtile as 4x4 grid of 16x16x32 bf16 MFMAs. K=128 staged once into LDS.
// Epilogue fuses -sqrt(max(a2+b2-2ab,0)) into the C write.
//
// Verified gfx950 layouts (learn_hip m89/m91):
//   A frag: lane holds A[m = lane&15][k = (lane>>4)*8 + t], t=0..7 (contiguous)
//   B frag: lane holds B[n = lane&15][k = (lane>>4)*8 + t]  (B^T input form)
//   C/D:    col = lane&15, row = (lane>>4)*4 + reg
// ---------------------------------------------------------------------------
__global__ __launch_bounds__(256, 2)
void dist_kernel(const __hip_bfloat16* __restrict__ abf, const __hip_bfloat16* __restrict__ bbf,
                 const float* __restrict__ a2, const float* __restrict__ b2,
                 float* __restrict__ out, int M) {
    __shared__ __hip_bfloat16 As[TILE][LDS_K];
    __shared__ __hip_bfloat16 Bs[TILE][LDS_K];

    const int rowBase = blockIdx.y * TILE;   // into z_anc (N)
    const int colBase = blockIdx.x * TILE;   // into z_pos_neg (M)
    const int tid = threadIdx.x;

    // Stage both 128x128 bf16 tiles: 16 chunks of 8 bf16 per row, coalesced.
    #pragma unroll
    for (int pass = 0; pass < 8; ++pass) {
        int idx = pass * 256 + tid;          // 0..2047
        int row = idx >> 4;
        int kc  = (idx & 15) * 8;
        uint4 va = *(const uint4*)(abf + ((size_t)(rowBase + row) * D_DIM + kc));
        *(uint4*)(&As[row][kc]) = va;
        uint4 vb = *(const uint4*)(bbf + ((size_t)(colBase + row) * D_DIM + kc));
        *(uint4*)(&Bs[row][kc]) = vb;
    }
    __syncthreads();

    const int wave = tid >> 6;
    const int lane = tid & 63;
    const int wr = (wave >> 1) * 64;         // wave row offset in tile
    const int wc = (wave & 1) * 64;          // wave col offset in tile
    const int lrow = lane & 15;
    const int lk = (lane >> 4) * 8;

    floatx4 acc[4][4] = {};
    #pragma unroll
    for (int ks = 0; ks < 4; ++ks) {
        const int k0 = ks * 32 + lk;
        short8 afr[4], bfr[4];
        #pragma unroll
        for (int i = 0; i < 4; ++i)
            afr[i] = *(const short8*)(&As[wr + i * 16 + lrow][k0]);
        #pragma unroll
        for (int j = 0; j < 4; ++j)
            bfr[j] = *(const short8*)(&Bs[wc + j * 16 + lrow][k0]);
        #pragma unroll
        for (int i = 0; i < 4; ++i)
            #pragma unroll
            for (int j = 0; j < 4; ++j)
                acc[i][j] = __builtin_amdgcn_mfma_f32_16x16x32_bf16(afr[i], bfr[j], acc[i][j], 0, 0, 0);
    }

    // Epilogue: C[n][m] -> out = -sqrt(max(a2[n] + b2[m] - 2*ab, 0))
    const int crow0 = rowBase + wr + (lane >> 4) * 4;
    const int ccol0 = colBase + wc + lrow;
    #pragma unroll
    for (int i = 0; i < 4; ++i) {
        #pragma unroll
        for (int r = 0; r < 4; ++r) {
            const int n = crow0 + i * 16 + r;
            const float an = a2[n];
            const size_t rowOff = (size_t)n * (size_t)M;
            #pragma unroll
            for (int j = 0; j < 4; ++j) {
                const int m = ccol0 + j * 16;
                float d2 = an + b2[m] - 2.0f * acc[i][j][r];
                d2 = fmaxf(d2, 0.0f);
                out[rowOff + m] = -sqrtf(d2);
            }
        }
    }
}

extern "C" void kernel_launch(void* const* d_in, const int* in_sizes, int n_in,
                              void* d_out, int out_size, void* d_ws, size_t ws_size,
                              hipStream_t stream) {
    const float* za = (const float*)d_in[0];
    const float* zb = (const float*)d_in[1];
    const int N = in_sizes[0] / D_DIM;   // 8192
    const int M = in_sizes[1] / D_DIM;   // 8192
    float* out = (float*)d_out;

    // workspace layout: abf [N*128 bf16] | bbf [M*128 bf16] | a2 [N f32] | b2 [M f32]
    char* ws = (char*)d_ws;
    __hip_bfloat16* abf = (__hip_bfloat16*)ws;
    __hip_bfloat16* bbf = (__hip_bfloat16*)(ws + (size_t)N * D_DIM * sizeof(__hip_bfloat16));
    float* a2 = (float*)(ws + (size_t)(N + M) * D_DIM * sizeof(__hip_bfloat16));
    float* b2 = a2 + N;

    prep_kernel<<<(N + M) / 4, 256, 0, stream>>>(za, zb, abf, bbf, a2, b2, N);

    dim3 grid(M / TILE, N / TILE);
    dist_kernel<<<grid, 256, 0, stream>>>(abf, bbf, a2, b2, out, M);
}